// Round 3
// baseline (60.285 us; speedup 1.0000x reference)
//
#include <hip/hip_runtime.h>

// HONU order-2, L=64: out[i] = b + sum_{j<=k} W[woff(j)+k-j] * x[i,j] * x[i,k]
// woff(j) = 64j - j(j-1)/2  (lex order of combinations_with_replacement)
//
// R3: 256 blocks x 1024 threads (16 waves = 4/SIMD). Block owns 64 rows
// (lane = row). X-tile staged in LDS CHUNK-MAJOR: tile4[q][row] (float4 at
// byte addr q*1024 + row*16) so every wave read is the canonical
// conflict-free aligned ds_read_b128 at base + lane*16 (~12 cyc). The 16
// waves split the triangular j-range with the compile-time balanced pairing
// (wave s: j in {2s,2s+1} U {62-2s,63-2s} -> exactly 134 FMAs each); all W
// indices are compile-time constants -> uniform scalar (s_load) batches.

#define ROWS 64

template <int J0, int J1>
__device__ __forceinline__ void accum_range(const float* __restrict__ W,
                                            const float (&x)[64],
                                            float& acc) {
#pragma unroll
  for (int j = J0; j < J1; ++j) {
    const int base = j * 64 - (j * (j - 1)) / 2;  // woff(j), compile-time
    float y = 0.0f;
#pragma unroll
    for (int k = j; k < 64; ++k) {
      y = __builtin_fmaf(W[base + (k - j)], x[k], y);
    }
    acc = __builtin_fmaf(x[j], y, acc);
  }
}

template <int S>
__device__ __forceinline__ float wave_work(const float* __restrict__ W,
                                           const float4* __restrict__ tile4,
                                           int lane) {
  // Wave S needs x[2S..63]; load chunks q0..15 as aligned float4 from LDS.
  constexpr int Q0 = (2 * S) >> 2;  // first needed chunk
  float x[64];
#pragma unroll
  for (int q = Q0; q < 16; ++q) {
    float4 v = tile4[q * 64 + lane];  // ds_read_b128, base + lane*16
    x[4 * q + 0] = v.x;
    x[4 * q + 1] = v.y;
    x[4 * q + 2] = v.z;
    x[4 * q + 3] = v.w;
  }
  float acc = 0.0f;
  accum_range<2 * S, 2 * S + 2>(W, x, acc);
  accum_range<62 - 2 * S, 64 - 2 * S>(W, x, acc);
  return acc;
}

__global__ __launch_bounds__(1024, 4) void honu_kernel(
    const float* __restrict__ X, const float* __restrict__ W,
    const float* __restrict__ Bias, float* __restrict__ out, int nrows) {
  __shared__ float4 tile4[16 * ROWS];  // chunk-major: [q][row], 16 KB
  __shared__ float part[16][64];       // 4 KB

  const int tid = threadIdx.x;
  const int lane = tid & 63;
  const int wave = tid >> 6;
  const int row0 = blockIdx.x * ROWS;

  // Coalesced staging: thread tid loads float4 (row r = tid>>4, chunk q =
  // tid&15) from global, stores chunk-major.
  {
    const int r = tid >> 4;
    const int q = tid & 15;
    float4 v = make_float4(0.f, 0.f, 0.f, 0.f);
    if (row0 + r < nrows) {
      v = reinterpret_cast<const float4*>(X)[(size_t)(row0 + r) * 16 + q];
    }
    tile4[q * 64 + r] = v;
  }
  __syncthreads();

  float acc = 0.0f;
  switch (wave) {  // wave-uniform branch
    case 0:  acc = wave_work<0>(W, tile4, lane);  break;
    case 1:  acc = wave_work<1>(W, tile4, lane);  break;
    case 2:  acc = wave_work<2>(W, tile4, lane);  break;
    case 3:  acc = wave_work<3>(W, tile4, lane);  break;
    case 4:  acc = wave_work<4>(W, tile4, lane);  break;
    case 5:  acc = wave_work<5>(W, tile4, lane);  break;
    case 6:  acc = wave_work<6>(W, tile4, lane);  break;
    case 7:  acc = wave_work<7>(W, tile4, lane);  break;
    case 8:  acc = wave_work<8>(W, tile4, lane);  break;
    case 9:  acc = wave_work<9>(W, tile4, lane);  break;
    case 10: acc = wave_work<10>(W, tile4, lane); break;
    case 11: acc = wave_work<11>(W, tile4, lane); break;
    case 12: acc = wave_work<12>(W, tile4, lane); break;
    case 13: acc = wave_work<13>(W, tile4, lane); break;
    default: acc = wave_work<15>(W, tile4, lane); break;
    case 14: acc = wave_work<14>(W, tile4, lane); break;
  }
  part[wave][lane] = acc;
  __syncthreads();

  if (tid < 64) {
    const int orow = row0 + tid;
    if (orow < nrows) {
      float r = Bias[0];
#pragma unroll
      for (int w = 0; w < 16; ++w) r += part[w][tid];
      out[orow] = r;
    }
  }
}

extern "C" void kernel_launch(void* const* d_in, const int* in_sizes, int n_in,
                              void* d_out, int out_size, void* d_ws,
                              size_t ws_size, hipStream_t stream) {
  const float* X = (const float*)d_in[0];     // (16384, 64) fp32
  const float* W = (const float*)d_in[1];     // (2145,) fp32 (first 2080 used)
  const float* Bias = (const float*)d_in[2];  // (1,) fp32
  float* out = (float*)d_out;                 // (16384,) fp32

  const int nrows = out_size;  // 16384
  const int grid = (nrows + ROWS - 1) / ROWS;
  honu_kernel<<<grid, 1024, 0, stream>>>(X, W, Bias, out, nrows);
}